// Round 1
// 991.957 us; speedup vs baseline: 1.0129x; 1.0129x over previous
//
#include <hip/hip_runtime.h>
#include <hip/hip_bf16.h>
#include <stdint.h>

// Problem constants (from reference setup_inputs)
#define M_TOK 8192      // B*S = 4*2048
#define K_IN  4096      // IN
#define N_OUT 11008     // OUT
#define G_CNT 128       // IN/32 groups per output row
#define BM 128
#define BN 256
#define TILES_M 64      // 8192/128
#define TILES_N 43      // 11008/256
#define KT_CNT 64       // K_IN/64 K-tiles
#define BUF_BYTES 24576 // A 128x64 + B 256x64 per K-tile buffer

typedef __attribute__((ext_vector_type(4)))  int   int4v;
typedef __attribute__((ext_vector_type(16))) int   int16v;
typedef __attribute__((ext_vector_type(4)))  float floatx4;

// async global->LDS, 16B per lane. LDS dest = wave-uniform base + lane*16.
__device__ __forceinline__ void gld16(const void* g, void* lds) {
  __builtin_amdgcn_global_load_lds(
      (const __attribute__((address_space(1))) unsigned int*)g,
      (__attribute__((address_space(3))) unsigned int*)lds,
      16, 0, 0);
}

// 64-byte-row LDS chunk swizzle: phys_chunk = chunk ^ swz(row).
// Rows 0..7 -> 8 distinct bank quads; rows mod 8 alias 2-way (free, m136).
__device__ __forceinline__ int swz(int r) { return (r & 3) ^ ((r >> 2) & 1); }

// ---------------------------------------------------------------------------
// Kernel 0: detect whether d_in[1] is int32-widened or raw int8.
__global__ void detect_kernel(const int* __restrict__ w, int* __restrict__ flag) {
  int bad = 0;
  int t = threadIdx.x;  // 64 threads
  for (int i = t; i < 4096; i += 64) {
    int v = w[i];
    bad |= (v < 0) | (v > 15);
  }
  bad = __any(bad);
  if (t == 0) *flag = bad ? 1 : 0;  // 1 => buffer is raw int8
}

// ---------------------------------------------------------------------------
// Kernel 1: groupwise dequant of int4 weights (fp32, exact vs reference),
// then per-row symmetric int8 re-quantization: w8 = round(w_dq/ws[n]),
// ws[n] = rowmax/127. One block per output row n; thread t handles
// k in [16t, 16t+16) (contained in group g = t/2).
__global__ __launch_bounds__(256) void wdq8_kernel(
    const int* __restrict__ w, const float* __restrict__ scales,
    const float* __restrict__ zeros, signed char* __restrict__ w8,
    float* __restrict__ wrsc, const int* __restrict__ flag) {
  int n = blockIdx.x;
  int t = threadIdx.x;
  int k0 = t << 4;
  int g  = k0 >> 5;
  float s = scales[(size_t)n * G_CNT + g];
  float z = zeros[(size_t)n * G_CNT + g];
  float wf[16];
  if (*flag == 0) {  // int32 elements
    const int4* p = (const int4*)(w + (size_t)n * K_IN + k0);
#pragma unroll
    for (int i = 0; i < 4; ++i) {
      int4 a = p[i];
      wf[4 * i + 0] = ((float)a.x - z) * s;
      wf[4 * i + 1] = ((float)a.y - z) * s;
      wf[4 * i + 2] = ((float)a.z - z) * s;
      wf[4 * i + 3] = ((float)a.w - z) * s;
    }
  } else {           // raw int8 bytes (values 0..15)
    const unsigned char* wb = (const unsigned char*)w;
    uint4 u = *(const uint4*)(wb + (size_t)n * K_IN + k0);
    unsigned int uu[4] = {u.x, u.y, u.z, u.w};
#pragma unroll
    for (int i = 0; i < 4; ++i)
#pragma unroll
      for (int b = 0; b < 4; ++b)
        wf[4 * i + b] = ((float)((uu[i] >> (8 * b)) & 0xFFu) - z) * s;
  }
  float mx = 0.f;
#pragma unroll
  for (int i = 0; i < 16; ++i) mx = fmaxf(mx, fabsf(wf[i]));
#pragma unroll
  for (int off = 32; off > 0; off >>= 1)
    mx = fmaxf(mx, __shfl_xor(mx, off, 64));
  __shared__ float sm[4];
  if ((t & 63) == 0) sm[t >> 6] = mx;
  __syncthreads();
  mx = fmaxf(fmaxf(sm[0], sm[1]), fmaxf(sm[2], sm[3]));
  mx = fmaxf(mx, 1e-20f);
  if (t == 0) wrsc[n] = mx / 127.f;
  float inv = 127.f / mx;
  unsigned int ob[4];
#pragma unroll
  for (int i = 0; i < 4; ++i) {
    unsigned int v = 0;
#pragma unroll
    for (int b = 0; b < 4; ++b) {
      int q = (int)rintf(wf[4 * i + b] * inv);
      q = q > 127 ? 127 : (q < -127 ? -127 : q);
      v |= ((unsigned int)(q & 0xFF)) << (8 * b);
    }
    ob[i] = v;
  }
  *(uint4*)(w8 + (size_t)n * K_IN + k0) = make_uint4(ob[0], ob[1], ob[2], ob[3]);
}

// ---------------------------------------------------------------------------
// Kernel 2: per-token abs-max + symmetric int8 quantization (EXACT vs
// reference: q = clip(rint(x / a_scale), -128, 127), fp32 division).
__global__ __launch_bounds__(256) void act8_kernel(
    const float* __restrict__ x, signed char* __restrict__ aq,
    float* __restrict__ ascale) {
  int row = blockIdx.x;
  const float4* xr = (const float4*)(x + (size_t)row * K_IN);
  int t = threadIdx.x;
  float4 v[4];
  float am = 0.f;
#pragma unroll
  for (int i = 0; i < 4; ++i) {
    v[i] = xr[i * 256 + t];
    am = fmaxf(am, fmaxf(fmaxf(fabsf(v[i].x), fabsf(v[i].y)),
                         fmaxf(fabsf(v[i].z), fabsf(v[i].w))));
  }
#pragma unroll
  for (int off = 32; off > 0; off >>= 1)
    am = fmaxf(am, __shfl_xor(am, off, 64));
  __shared__ float sm[4];
  if ((t & 63) == 0) sm[t >> 6] = am;
  __syncthreads();
  am = fmaxf(fmaxf(sm[0], sm[1]), fmaxf(sm[2], sm[3]));
  float as_ = fmaxf(am, 1e-12f) / 127.f;
  if (t == 0) ascale[row] = as_;
  int* op = (int*)(aq + (size_t)row * K_IN);
#pragma unroll
  for (int i = 0; i < 4; ++i) {
    float qf[4] = {v[i].x, v[i].y, v[i].z, v[i].w};
    unsigned int pk = 0;
#pragma unroll
    for (int b = 0; b < 4; ++b) {
      float q = fminf(fmaxf(rintf(qf[b] / as_), -128.f), 127.f);
      pk |= ((unsigned int)((int)q & 0xFF)) << (8 * b);
    }
    op[i * 256 + t] = (int)pk;  // coalesced 4B stores
  }
}

// ---------------------------------------------------------------------------
// Kernel 3: int8 GEMM  C[m,n] = ascale[m] * ws[n] * sum_k A8[m,k] * W8[n,k]
// 128x256 block, 4 waves (2x2 grid), each wave 64x128 = 2x4 of 32x32x32 i8
// MFMA, i32 accumulation over full K (no overflow: 128*127*4096 < 2^31).
//
// T3/T4 pipeline (counted vmcnt, never drained in main loop):
//   3 LDS buffers (72 KB, 2 blocks/CU). Iteration kt:
//     issue stage(tile kt+2) -> buf[(kt+2)%3]   (6 gld16/wave)
//     s_waitcnt vmcnt(12)   == tiles kt+1,kt+2 stay in flight; kt landed
//     s_barrier;  compute tile kt from buf[kt%3];  s_barrier
//   buf[(kt+2)%3] held tile kt-1, whose reads finished before the previous
//   end-barrier -> DMA writes can land any time after issue. All ds_reads
//   are consumed by MFMAs before the end barrier (compiler lgkm waits), so
//   raw s_barrier needs no lgkm drain. Tail peels kt=62 (vmcnt 6), 63 (0).
// T5: s_setprio(1) around each 8-MFMA cluster.
__global__ __launch_bounds__(256, 2) void gemm_i8_kernel(
    const signed char* __restrict__ A8,   // [M,K] int8
    const signed char* __restrict__ W8,   // [N,K] int8
    const float* __restrict__ Ascale,     // [M]
    const float* __restrict__ Wrsc,       // [N]
    float* __restrict__ C) {              // [M,N]
  __shared__ __attribute__((aligned(16))) signed char ldsbuf[3 * BUF_BYTES];

  int bx = blockIdx.x;
  // supertile: bands of 8 M-tiles for B-tile L2 reuse
  int band = bx / (8 * TILES_N);
  int rem  = bx % (8 * TILES_N);
  int tm = band * 8 + (rem & 7);
  int tn = rem >> 3;
  int m0 = tm * BM, n0 = tn * BN;

  int t = threadIdx.x;
  int lane = t & 63;
  int w = t >> 6;
  int wm = (w >> 1) * 64, wn = (w & 1) * 128;  // wave sub-tile origin
  int half = lane >> 5, r31 = lane & 31;

  // --- staging geometry (each gld16 covers 16 rows x 64 B) ---
  // A: wave w stages tile rows w*32 .. w*32+31 (2 gld16)
  // B: wave w stages tile rows w*64 .. w*64+63 (4 gld16)
  int lrow = lane >> 2;        // 0..15 within a gld16
  int lchunk = lane & 3;       // physical 16B chunk
  const signed char* pA[2];
  const signed char* pB[4];
#pragma unroll
  for (int r = 0; r < 2; ++r) {
    int grow = w * 32 + r * 16 + lrow;
    int scol = (lchunk ^ swz(grow)) << 4;   // logical source chunk
    pA[r] = A8 + (size_t)(m0 + grow) * K_IN + scol;
  }
#pragma unroll
  for (int r = 0; r < 4; ++r) {
    int grow = w * 64 + r * 16 + lrow;
    int scol = (lchunk ^ swz(grow)) << 4;
    pB[r] = W8 + (size_t)(n0 + grow) * K_IN + scol;
  }

  // --- fragment read offsets (within one buffer) ---
  // 32x32x32 i8 frag: row/col = lane&31, 16 consecutive K-bytes selected by
  // chunk c = kstep*2 + (lane>>5). K-permutation cancels between A and B.
  int aoff[2][2], boff[4][2];
#pragma unroll
  for (int i = 0; i < 2; ++i) {
    int R = wm + i * 32 + r31;
    int sw = swz(R);
#pragma unroll
    for (int ks = 0; ks < 2; ++ks)
      aoff[i][ks] = R * 64 + (((ks * 2 + half) ^ sw) << 4);
  }
#pragma unroll
  for (int j = 0; j < 4; ++j) {
    int R = wn + j * 32 + r31;
    int sw = swz(R);
#pragma unroll
    for (int ks = 0; ks < 2; ++ks)
      boff[j][ks] = R * 64 + (((ks * 2 + half) ^ sw) << 4);
  }

  int16v acc[2][4];
#pragma unroll
  for (int i = 0; i < 2; ++i)
#pragma unroll
    for (int j = 0; j < 4; ++j)
#pragma unroll
      for (int e = 0; e < 16; ++e) acc[i][j][e] = 0;

  // stage one K-tile into buffer at byte offset bo, advance global pointers
  auto STAGE = [&](int bo) {
    char* lAb = (char*)ldsbuf + bo;
    char* lBb = lAb + 8192;
#pragma unroll
    for (int r = 0; r < 2; ++r)
      gld16(pA[r], lAb + (w * 32 + r * 16) * 64);
#pragma unroll
    for (int r = 0; r < 4; ++r)
      gld16(pB[r], lBb + (w * 64 + r * 16) * 64);
#pragma unroll
    for (int r = 0; r < 2; ++r) pA[r] += 64;
#pragma unroll
    for (int r = 0; r < 4; ++r) pB[r] += 64;
  };

  auto COMPUTE = [&](int bo) {
    const char* lAb = (const char*)ldsbuf + bo;
    const char* lBb = lAb + 8192;
#pragma unroll
    for (int ks = 0; ks < 2; ++ks) {
      int4v af[2], bf[4];
#pragma unroll
      for (int i = 0; i < 2; ++i) af[i] = *(const int4v*)(lAb + aoff[i][ks]);
#pragma unroll
      for (int j = 0; j < 4; ++j) bf[j] = *(const int4v*)(lBb + boff[j][ks]);
      __builtin_amdgcn_s_setprio(1);
#pragma unroll
      for (int i = 0; i < 2; ++i)
#pragma unroll
        for (int j = 0; j < 4; ++j)
          acc[i][j] = __builtin_amdgcn_mfma_i32_32x32x32_i8(af[i], bf[j], acc[i][j], 0, 0, 0);
      __builtin_amdgcn_s_setprio(0);
    }
  };

  // prologue: tiles 0 and 1 in flight
  STAGE(0);
  STAGE(BUF_BYTES);

  int curo = 0;               // compute-buffer byte offset (tile kt)
  int stgo = 2 * BUF_BYTES;   // stage-buffer byte offset  (tile kt+2)

  for (int kt = 0; kt < KT_CNT - 2; ++kt) {
    STAGE(stgo);
    // tiles kt+1,kt+2 (12 loads) stay in flight; tile kt guaranteed landed
    asm volatile("s_waitcnt vmcnt(12)" ::: "memory");
    __builtin_amdgcn_s_barrier();
    asm volatile("" ::: "memory");
    COMPUTE(curo);
    asm volatile("" ::: "memory");
    __builtin_amdgcn_s_barrier();
    asm volatile("" ::: "memory");
    curo = (curo == 2 * BUF_BYTES) ? 0 : curo + BUF_BYTES;
    stgo = (stgo == 2 * BUF_BYTES) ? 0 : stgo + BUF_BYTES;
  }
  // kt = 62: tile 63's 6 loads may remain in flight
  asm volatile("s_waitcnt vmcnt(6)" ::: "memory");
  __builtin_amdgcn_s_barrier();
  asm volatile("" ::: "memory");
  COMPUTE(curo);
  curo = (curo == 2 * BUF_BYTES) ? 0 : curo + BUF_BYTES;
  // kt = 63: drain everything (no stages remain)
  asm volatile("" ::: "memory");
  asm volatile("s_waitcnt vmcnt(0)" ::: "memory");
  __builtin_amdgcn_s_barrier();
  asm volatile("" ::: "memory");
  COMPUTE(curo);

  // epilogue: C tile (i,j): col n = n0+wn+j*32+(lane&31) (reg-independent),
  // row m = m0+wm+i*32 + (reg&3) + 8*(reg>>2) + 4*half  (measured, m101)
  float wsv[4];
#pragma unroll
  for (int j = 0; j < 4; ++j) wsv[j] = Wrsc[n0 + wn + j * 32 + r31];
#pragma unroll
  for (int i = 0; i < 2; ++i) {
#pragma unroll
    for (int rh = 0; rh < 4; ++rh) {      // reg>>2
#pragma unroll
      for (int rl = 0; rl < 4; ++rl) {    // reg&3
        int rg = rh * 4 + rl;
        int gm = m0 + wm + i * 32 + rl + 8 * rh + 4 * half;
        float s = Ascale[gm];
        float* crow = C + (size_t)gm * N_OUT + n0 + wn + r31;
#pragma unroll
        for (int j = 0; j < 4; ++j)
          crow[j * 32] = s * wsv[j] * (float)acc[i][j][rg];
      }
    }
  }
}

// ---------------------------------------------------------------------------
extern "C" void kernel_launch(void* const* d_in, const int* in_sizes, int n_in,
                              void* d_out, int out_size, void* d_ws, size_t ws_size,
                              hipStream_t stream) {
  const float* x      = (const float*)d_in[0];  // [4,2048,4096] f32
  const int*   wraw   = (const int*)d_in[1];    // [11008,4096] int (detected)
  const float* scales = (const float*)d_in[2];  // [11008,128] f32
  const float* zeros  = (const float*)d_in[3];  // [11008,128] f32
  float* out = (float*)d_out;                   // [8192,11008] f32

  char* ws = (char*)d_ws;
  signed char* W8 = (signed char*)ws;                                  // 45,088,768 B
  signed char* A8 = (signed char*)(ws + (size_t)N_OUT * K_IN);         // 33,554,432 B
  float* Wrsc   = (float*)(ws + (size_t)N_OUT * K_IN + (size_t)M_TOK * K_IN);
  float* Ascale = Wrsc + N_OUT;
  int* flag = (int*)(Ascale + M_TOK);

  detect_kernel<<<1, 64, 0, stream>>>(wraw, flag);
  wdq8_kernel<<<N_OUT, 256, 0, stream>>>(wraw, scales, zeros, W8, Wrsc, flag);
  act8_kernel<<<M_TOK, 256, 0, stream>>>(x, A8, Ascale);
  gemm_i8_kernel<<<TILES_M * TILES_N, 256, 0, stream>>>(A8, W8, Ascale, Wrsc, out);
}

// Round 2
// 945.599 us; speedup vs baseline: 1.0626x; 1.0490x over previous
//
#include <hip/hip_runtime.h>
#include <hip/hip_bf16.h>
#include <stdint.h>

// Problem constants (from reference setup_inputs)
#define M_TOK 8192      // B*S = 4*2048
#define K_IN  4096      // IN
#define N_OUT 11008     // OUT
#define G_CNT 128       // IN/32 groups per output row
#define BM 256
#define BN 256
#define TILES_M 32      // 8192/256
#define TILES_N 43      // 11008/256
#define KT_CNT 64       // K_IN/64 K-tiles
#define ABYTES 16384    // A tile 256x64 int8
#define BUF_BYTES 32768 // A 256x64 + B 256x64 per K-tile buffer

typedef __attribute__((ext_vector_type(4)))  int   int4v;
typedef __attribute__((ext_vector_type(16))) int   int16v;

// async global->LDS, 16B per lane. LDS dest = wave-uniform base + lane*16.
__device__ __forceinline__ void gld16(const void* g, void* lds) {
  __builtin_amdgcn_global_load_lds(
      (const __attribute__((address_space(1))) unsigned int*)g,
      (__attribute__((address_space(3))) unsigned int*)lds,
      16, 0, 0);
}

// 64-byte-row LDS chunk swizzle: phys_chunk = chunk ^ swz(row).
__device__ __forceinline__ int swz(int r) { return (r & 3) ^ ((r >> 2) & 1); }

// ---------------------------------------------------------------------------
// Kernel 0: detect whether d_in[1] is int32-widened or raw int8.
__global__ void detect_kernel(const int* __restrict__ w, int* __restrict__ flag) {
  int bad = 0;
  int t = threadIdx.x;  // 64 threads
  for (int i = t; i < 4096; i += 64) {
    int v = w[i];
    bad |= (v < 0) | (v > 15);
  }
  bad = __any(bad);
  if (t == 0) *flag = bad ? 1 : 0;  // 1 => buffer is raw int8
}

// ---------------------------------------------------------------------------
// Kernel 1: groupwise dequant of int4 weights (fp32, exact vs reference),
// then per-row symmetric int8 re-quantization.
__global__ __launch_bounds__(256) void wdq8_kernel(
    const int* __restrict__ w, const float* __restrict__ scales,
    const float* __restrict__ zeros, signed char* __restrict__ w8,
    float* __restrict__ wrsc, const int* __restrict__ flag) {
  int n = blockIdx.x;
  int t = threadIdx.x;
  int k0 = t << 4;
  int g  = k0 >> 5;
  float s = scales[(size_t)n * G_CNT + g];
  float z = zeros[(size_t)n * G_CNT + g];
  float wf[16];
  if (*flag == 0) {  // int32 elements
    const int4* p = (const int4*)(w + (size_t)n * K_IN + k0);
#pragma unroll
    for (int i = 0; i < 4; ++i) {
      int4 a = p[i];
      wf[4 * i + 0] = ((float)a.x - z) * s;
      wf[4 * i + 1] = ((float)a.y - z) * s;
      wf[4 * i + 2] = ((float)a.z - z) * s;
      wf[4 * i + 3] = ((float)a.w - z) * s;
    }
  } else {           // raw int8 bytes (values 0..15)
    const unsigned char* wb = (const unsigned char*)w;
    uint4 u = *(const uint4*)(wb + (size_t)n * K_IN + k0);
    unsigned int uu[4] = {u.x, u.y, u.z, u.w};
#pragma unroll
    for (int i = 0; i < 4; ++i)
#pragma unroll
      for (int b = 0; b < 4; ++b)
        wf[4 * i + b] = ((float)((uu[i] >> (8 * b)) & 0xFFu) - z) * s;
  }
  float mx = 0.f;
#pragma unroll
  for (int i = 0; i < 16; ++i) mx = fmaxf(mx, fabsf(wf[i]));
#pragma unroll
  for (int off = 32; off > 0; off >>= 1)
    mx = fmaxf(mx, __shfl_xor(mx, off, 64));
  __shared__ float sm[4];
  if ((t & 63) == 0) sm[t >> 6] = mx;
  __syncthreads();
  mx = fmaxf(fmaxf(sm[0], sm[1]), fmaxf(sm[2], sm[3]));
  mx = fmaxf(mx, 1e-20f);
  if (t == 0) wrsc[n] = mx / 127.f;
  float inv = 127.f / mx;
  unsigned int ob[4];
#pragma unroll
  for (int i = 0; i < 4; ++i) {
    unsigned int v = 0;
#pragma unroll
    for (int b = 0; b < 4; ++b) {
      int q = (int)rintf(wf[4 * i + b] * inv);
      q = q > 127 ? 127 : (q < -127 ? -127 : q);
      v |= ((unsigned int)(q & 0xFF)) << (8 * b);
    }
    ob[i] = v;
  }
  *(uint4*)(w8 + (size_t)n * K_IN + k0) = make_uint4(ob[0], ob[1], ob[2], ob[3]);
}

// ---------------------------------------------------------------------------
// Kernel 2: per-token abs-max + symmetric int8 quantization (EXACT vs
// reference: q = clip(rint(x / a_scale), -128, 127), fp32 division).
__global__ __launch_bounds__(256) void act8_kernel(
    const float* __restrict__ x, signed char* __restrict__ aq,
    float* __restrict__ ascale) {
  int row = blockIdx.x;
  const float4* xr = (const float4*)(x + (size_t)row * K_IN);
  int t = threadIdx.x;
  float4 v[4];
  float am = 0.f;
#pragma unroll
  for (int i = 0; i < 4; ++i) {
    v[i] = xr[i * 256 + t];
    am = fmaxf(am, fmaxf(fmaxf(fabsf(v[i].x), fabsf(v[i].y)),
                         fmaxf(fabsf(v[i].z), fabsf(v[i].w))));
  }
#pragma unroll
  for (int off = 32; off > 0; off >>= 1)
    am = fmaxf(am, __shfl_xor(am, off, 64));
  __shared__ float sm[4];
  if ((t & 63) == 0) sm[t >> 6] = am;
  __syncthreads();
  am = fmaxf(fmaxf(sm[0], sm[1]), fmaxf(sm[2], sm[3]));
  float as_ = fmaxf(am, 1e-12f) / 127.f;
  if (t == 0) ascale[row] = as_;
  int* op = (int*)(aq + (size_t)row * K_IN);
#pragma unroll
  for (int i = 0; i < 4; ++i) {
    float qf[4] = {v[i].x, v[i].y, v[i].z, v[i].w};
    unsigned int pk = 0;
#pragma unroll
    for (int b = 0; b < 4; ++b) {
      float q = fminf(fmaxf(rintf(qf[b] / as_), -128.f), 127.f);
      pk |= ((unsigned int)((int)q & 0xFF)) << (8 * b);
    }
    op[i * 256 + t] = (int)pk;  // coalesced 4B stores
  }
}

// ---------------------------------------------------------------------------
// Kernel 3: int8 GEMM  C[m,n] = ascale[m] * ws[n] * sum_k A8[m,k] * W8[n,k]
// 256x256 block, 512 threads = 8 waves (2M x 4N), wave tile 128x64 =
// 4x2 frags of 32x32x32 i8 MFMA, i32 accumulation over full K.
//
// 8-phase-style schedule (T3+T4+T5, ported from the 256^2 bf16 template):
//   4 phases per K-tile, each phase:
//     { ds_read 2-4 x b128 ; issue 1 gld16 (tile kt+2) ; fence ;
//       [phi3 only: s_waitcnt vmcnt(4)] ; s_barrier ;
//       setprio(1) ; 4 x MFMA ; setprio(0) ; fence ; s_barrier }
//   Tri-buffer (3 x 32 KB). vmcnt(4) sits BEFORE phi3's barrier so the
//   barrier makes "tile kt+1 landed" block-wide (per-wave vmcnt alone only
//   covers this wave's own 4 loads). Slot (kt+2)%3 == (kt-1)%3 is first
//   written only after the barrier proving kt-1's ds_reads are in regs.
//   Main loop never drains vmcnt to 0.
__global__ __launch_bounds__(512, 2) void gemm_i8_kernel(
    const signed char* __restrict__ A8,   // [M,K] int8
    const signed char* __restrict__ W8,   // [N,K] int8
    const float* __restrict__ Ascale,     // [M]
    const float* __restrict__ Wrsc,       // [N]
    float* __restrict__ C) {              // [M,N]
  __shared__ __attribute__((aligned(16))) signed char ldsbuf[3 * BUF_BYTES];

  int bx = blockIdx.x;
  // supertile: bands of 8 M-tiles for B-tile L2 reuse (32 % 8 == 0)
  int band = bx / (8 * TILES_N);
  int rem  = bx % (8 * TILES_N);
  int tm = band * 8 + (rem & 7);
  int tn = rem >> 3;
  int m0 = tm * BM, n0 = tn * BN;

  int t = threadIdx.x;
  int lane = t & 63;
  int w = t >> 6;                       // 0..7
  int wm = (w >> 2) * 128;              // wave M origin: 0 or 128
  int wn = (w & 3) * 64;                // wave N origin: 0,64,128,192
  int half = lane >> 5, r31 = lane & 31;

  // --- staging geometry: each gld16 covers 16 rows x 64 B ---
  // A: wave w stages rows w*32 .. w*32+31 (2 gld16); B identical.
  int lrow = lane >> 2;        // 0..15 within a gld16
  int lchunk = lane & 3;       // physical 16B chunk
  const signed char* pA[2];
  const signed char* pB[2];
#pragma unroll
  for (int r = 0; r < 2; ++r) {
    int grow = w * 32 + r * 16 + lrow;
    int scol = (lchunk ^ swz(grow)) << 4;   // pre-swizzled source chunk
    pA[r] = A8 + (size_t)(m0 + grow) * K_IN + scol;
    pB[r] = W8 + (size_t)(n0 + grow) * K_IN + scol;
  }
  int sArow0 = (w * 32) * 64;
  int sArow1 = (w * 32 + 16) * 64;

  // --- fragment read offsets (within one buffer; A at 0, B at ABYTES) ---
  // chunk c = ks*2 + (lane>>5); phys = c ^ swz(row). K-permutation cancels
  // between A and B.
  int aoff[4][2], boff[2][2];
#pragma unroll
  for (int i = 0; i < 4; ++i) {
    int R = wm + i * 32 + r31;
    int sw = swz(R);
#pragma unroll
    for (int ks = 0; ks < 2; ++ks)
      aoff[i][ks] = R * 64 + (((ks * 2 + half) ^ sw) << 4);
  }
#pragma unroll
  for (int j = 0; j < 2; ++j) {
    int R = wn + j * 32 + r31;
    int sw = swz(R);
#pragma unroll
    for (int ks = 0; ks < 2; ++ks)
      boff[j][ks] = R * 64 + (((ks * 2 + half) ^ sw) << 4);
  }

  int16v acc[4][2];
#pragma unroll
  for (int i = 0; i < 4; ++i)
#pragma unroll
    for (int j = 0; j < 2; ++j)
#pragma unroll
      for (int e = 0; e < 16; ++e) acc[i][j][e] = 0;

#define MFMA_QUAD(I0, I1, Af0, Af1, Bf0, Bf1)                                   \
  __builtin_amdgcn_s_setprio(1);                                                \
  acc[I0][0] = __builtin_amdgcn_mfma_i32_32x32x32_i8(Af0, Bf0, acc[I0][0],0,0,0);\
  acc[I0][1] = __builtin_amdgcn_mfma_i32_32x32x32_i8(Af0, Bf1, acc[I0][1],0,0,0);\
  acc[I1][0] = __builtin_amdgcn_mfma_i32_32x32x32_i8(Af1, Bf0, acc[I1][0],0,0,0);\
  acc[I1][1] = __builtin_amdgcn_mfma_i32_32x32x32_i8(Af1, Bf1, acc[I1][1],0,0,0);\
  __builtin_amdgcn_s_setprio(0);

#define FENCE asm volatile("" ::: "memory")

  // One K-tile: 4 phases. DO_STG: issue gld16s for tile kt+2.
  // VM_WAIT: asm wait placed before phi3's first barrier.
#define TILE_BODY(DO_STG, VM_WAIT)                                              \
  {                                                                             \
    const char* lAb = (const char*)ldsbuf + curo;                               \
    const char* lBb = lAb + ABYTES;                                             \
    char* sAb = (char*)ldsbuf + stgo;                                           \
    char* sBb = sAb + ABYTES;                                                   \
    int4v a0, a1, b0, b1;                                                       \
    /* phi0: ks0, i={0,1}; read b ks0 (held through phi1) */                    \
    a0 = *(const int4v*)(lAb + aoff[0][0]);                                     \
    a1 = *(const int4v*)(lAb + aoff[1][0]);                                     \
    b0 = *(const int4v*)(lBb + boff[0][0]);                                     \
    b1 = *(const int4v*)(lBb + boff[1][0]);                                     \
    if (DO_STG) { gld16(pA[0], sAb + sArow0); pA[0] += 64; }                    \
    FENCE; __builtin_amdgcn_s_barrier();                                        \
    MFMA_QUAD(0, 1, a0, a1, b0, b1)                                             \
    FENCE; __builtin_amdgcn_s_barrier();                                        \
    /* phi1: ks0, i={2,3} */                                                    \
    a0 = *(const int4v*)(lAb + aoff[2][0]);                                     \
    a1 = *(const int4v*)(lAb + aoff[3][0]);                                     \
    if (DO_STG) { gld16(pA[1], sAb + sArow1); pA[1] += 64; }                    \
    FENCE; __builtin_amdgcn_s_barrier();                                        \
    MFMA_QUAD(2, 3, a0, a1, b0, b1)                                             \
    FENCE; __builtin_amdgcn_s_barrier();                                        \
    /* phi2: ks1, i={0,1}; fresh b ks1 */                                       \
    a0 = *(const int4v*)(lAb + aoff[0][1]);                                     \
    a1 = *(const int4v*)(lAb + aoff[1][1]);                                     \
    b0 = *(const int4v*)(lBb + boff[0][1]);                                     \
    b1 = *(const int4v*)(lBb + boff[1][1]);                                     \
    if (DO_STG) { gld16(pB[0], sBb + sArow0); pB[0] += 64; }                    \
    FENCE; __builtin_amdgcn_s_barrier();                                        \
    MFMA_QUAD(0, 1, a0, a1, b0, b1)                                             \
    FENCE; __builtin_amdgcn_s_barrier();                                        \
    /* phi3: ks1, i={2,3}; per-K-tile counted vmcnt before the barrier */       \
    a0 = *(const int4v*)(lAb + aoff[2][1]);                                     \
    a1 = *(const int4v*)(lAb + aoff[3][1]);                                     \
    if (DO_STG) { gld16(pB[1], sBb + sArow1); pB[1] += 64; }                    \
    FENCE;                                                                      \
    VM_WAIT;                                                                    \
    __builtin_amdgcn_s_barrier();                                               \
    MFMA_QUAD(2, 3, a0, a1, b0, b1)                                             \
    FENCE; __builtin_amdgcn_s_barrier();                                        \
  }

  // stage a full K-tile into slot at byte offset bo (prologue only)
  auto STAGE = [&](int bo) {
    char* sAb = (char*)ldsbuf + bo;
    char* sBb = sAb + ABYTES;
    gld16(pA[0], sAb + sArow0); pA[0] += 64;
    gld16(pA[1], sAb + sArow1); pA[1] += 64;
    gld16(pB[0], sBb + sArow0); pB[0] += 64;
    gld16(pB[1], sBb + sArow1); pB[1] += 64;
  };

  // prologue: tiles 0,1 staged; tile 0 landed block-wide before loop
  STAGE(0);
  STAGE(BUF_BYTES);
  asm volatile("s_waitcnt vmcnt(4)" ::: "memory");  // tile 0 landed
  __builtin_amdgcn_s_barrier();

  int curo = 0;               // compute slot (tile kt)
  int stgo = 2 * BUF_BYTES;   // stage slot   (tile kt+2)

  for (int kt = 0; kt < KT_CNT - 2; ++kt) {
    // phi3 waits vmcnt(4): kt+2's 4 issues (this tile) may remain in flight;
    // everything older (incl. kt+1's loads) forced complete -> after the
    // barrier, tile kt+1 is landed block-wide.
    TILE_BODY(1, asm volatile("s_waitcnt vmcnt(4)" ::: "memory"))
    curo = (curo == 2 * BUF_BYTES) ? 0 : curo + BUF_BYTES;
    stgo = (stgo == 2 * BUF_BYTES) ? 0 : stgo + BUF_BYTES;
  }
  // kt = 62: no staging; drain tile 63's 4 loads before its compute
  TILE_BODY(0, asm volatile("s_waitcnt vmcnt(0)" ::: "memory"))
  curo = (curo == 2 * BUF_BYTES) ? 0 : curo + BUF_BYTES;
  // kt = 63: no staging, nothing outstanding
  TILE_BODY(0, )

  // epilogue: C tile (i,j): col n = n0+wn+j*32+(lane&31) (reg-independent),
  // row m = m0+wm+i*32 + (reg&3) + 8*(reg>>2) + 4*half  (measured, m101)
  float wsv[2];
#pragma unroll
  for (int j = 0; j < 2; ++j) wsv[j] = Wrsc[n0 + wn + j * 32 + r31];
#pragma unroll
  for (int i = 0; i < 4; ++i) {
#pragma unroll
    for (int rh = 0; rh < 4; ++rh) {      // reg>>2
#pragma unroll
      for (int rl = 0; rl < 4; ++rl) {    // reg&3
        int rg = rh * 4 + rl;
        int gm = m0 + wm + i * 32 + rl + 8 * rh + 4 * half;
        float s = Ascale[gm];
        float* crow = C + (size_t)gm * N_OUT + n0 + wn + r31;
#pragma unroll
        for (int j = 0; j < 2; ++j)
          crow[j * 32] = s * wsv[j] * (float)acc[i][j][rg];
      }
    }
  }
#undef TILE_BODY
#undef MFMA_QUAD
#undef FENCE
}

// ---------------------------------------------------------------------------
extern "C" void kernel_launch(void* const* d_in, const int* in_sizes, int n_in,
                              void* d_out, int out_size, void* d_ws, size_t ws_size,
                              hipStream_t stream) {
  const float* x      = (const float*)d_in[0];  // [4,2048,4096] f32
  const int*   wraw   = (const int*)d_in[1];    // [11008,4096] int (detected)
  const float* scales = (const float*)d_in[2];  // [11008,128] f32
  const float* zeros  = (const float*)d_in[3];  // [11008,128] f32
  float* out = (float*)d_out;                   // [8192,11008] f32

  char* ws = (char*)d_ws;
  signed char* W8 = (signed char*)ws;                                  // 45,088,768 B
  signed char* A8 = (signed char*)(ws + (size_t)N_OUT * K_IN);         // 33,554,432 B
  float* Wrsc   = (float*)(ws + (size_t)N_OUT * K_IN + (size_t)M_TOK * K_IN);
  float* Ascale = Wrsc + N_OUT;
  int* flag = (int*)(Ascale + M_TOK);

  detect_kernel<<<1, 64, 0, stream>>>(wraw, flag);
  wdq8_kernel<<<N_OUT, 256, 0, stream>>>(wraw, scales, zeros, W8, Wrsc, flag);
  act8_kernel<<<M_TOK, 256, 0, stream>>>(x, A8, Ascale);
  gemm_i8_kernel<<<TILES_M * TILES_N, 512, 0, stream>>>(A8, W8, Ascale, Wrsc, out);
}